// Round 1
// baseline (1499.369 us; speedup 1.0000x reference)
//
#include <hip/hip_runtime.h>
#include <math.h>

#define SEQ 8192
#define TAGS 128

// ---------------- complex helpers ----------------
__device__ __forceinline__ float2 mkc(float re, float im){ return make_float2(re, im); }

// RX(theta) on wire w of a 2-qubit state s[4] (idx = w0*2 + w1)
__device__ __forceinline__ void rx_gate(float2* s, float th, int w){
    float c = cosf(0.5f*th), sn = sinf(0.5f*th);
    int a0 = 0, b0 = (w==0)?2:1;
    int a1 = (w==0)?1:2, b1 = 3;
    float2 A=s[a0], B=s[b0];
    s[a0] = mkc(c*A.x + sn*B.y, c*A.y - sn*B.x);
    s[b0] = mkc(sn*A.y + c*B.x, -sn*A.x + c*B.y);
    A=s[a1]; B=s[b1];
    s[a1] = mkc(c*A.x + sn*B.y, c*A.y - sn*B.x);
    s[b1] = mkc(sn*A.y + c*B.x, -sn*A.x + c*B.y);
}

// rot2(r,phi) on wire w:  na = cr*A - e^{i phi} sr * B ; nb = e^{-i phi} sr * A + cr * B
__device__ __forceinline__ void rot2_gate(float2* s, float r, float phi, int w){
    float cr = cosf(r), sr = sinf(r), cp = cosf(phi), sp = sinf(phi);
    int a0 = 0, b0 = (w==0)?2:1;
    int a1 = (w==0)?1:2, b1 = 3;
    #pragma unroll
    for (int p = 0; p < 2; ++p){
        int a = p ? a1 : a0, bi = p ? b1 : b0;
        float2 A = s[a], B = s[bi];
        float2 eB = mkc(cp*B.x - sp*B.y, cp*B.y + sp*B.x);   // e^{+i phi} * B
        float2 eA = mkc(cp*A.x + sp*A.y, cp*A.y - sp*A.x);   // e^{-i phi} * A
        s[a]  = mkc(cr*A.x - sr*eB.x, cr*A.y - sr*eB.y);
        s[bi] = mkc(sr*eA.x + cr*B.x, sr*eA.y + cr*B.y);
    }
}

// diag(1, e^{ik}) on wire w
__device__ __forceinline__ void phase_gate(float2* s, float k, int w){
    float ck = cosf(k), sk = sinf(k);
    int i0 = (w==0)?2:1, i1 = 3;
    float2 A = s[i0];
    s[i0] = mkc(ck*A.x - sk*A.y, ck*A.y + sk*A.x);
    A = s[i1];
    s[i1] = mkc(ck*A.x - sk*A.y, ck*A.y + sk*A.x);
}

// beamsplitter on flat indices 1,2
__device__ __forceinline__ void bs_gate(float2* s, float bst, float bsp){
    float ct = cosf(bst), st = sinf(bst), cp = cosf(bsp), sp = sinf(bsp);
    float2 s1 = s[1], s2 = s[2];
    float2 e2 = mkc(cp*s2.x - sp*s2.y, cp*s2.y + sp*s2.x);   // e^{+i phi} s2
    float2 e1 = mkc(cp*s1.x + sp*s1.y, cp*s1.y - sp*s1.x);   // e^{-i phi} s1
    s[1] = mkc(ct*s1.x - st*e2.x, ct*s1.y - st*e2.y);
    s[2] = mkc(st*e1.x + ct*s2.x, st*e1.y + ct*s2.y);
}

__device__ __forceinline__ void fraud_layer(float2* s,
        float bst, float bsp, float ph0, float ph1,
        float sr0, float sp0, float sr1, float sp1,
        float dr0, float dp0, float dr1, float dp1,
        float k0, float k1){
    bs_gate(s, bst, bsp);
    rx_gate(s, ph0, 0); rx_gate(s, ph1, 1);
    rot2_gate(s, sr0, sp0, 0); rot2_gate(s, sr1, sp1, 1);
    bs_gate(s, bst, bsp);
    rx_gate(s, ph0, 0); rx_gate(s, ph1, 1);
    rot2_gate(s, dr0, dp0, 0); rot2_gate(s, dr1, dp1, 1);
    phase_gate(s, k0, 0); phase_gate(s, k1, 1);
}

// ---------------- K1: photonic feats + preX (transposed, scaled) ----------------
__global__ __launch_bounds__(256) void k1_feats_pre(
        const float* __restrict__ emb, const float* __restrict__ Wg,
        const float* __restrict__ bg, const float* __restrict__ theta,
        const int* __restrict__ sent, float* __restrict__ preX){
    int t = blockIdx.x * blockDim.x + threadIdx.x;
    if (t >= SEQ) return;
    int idx = sent[t];
    float x0 = emb[idx*2 + 0], x1 = emb[idx*2 + 1];
    float c0 = cosf(0.5f*x0), s0 = sinf(0.5f*x0);
    float c1 = cosf(0.5f*x1), s1 = sinf(0.5f*x1);
    float2 s[4];
    s[0] = mkc(c0*c1, 0.f);
    s[1] = mkc(0.f, -c0*s1);
    s[2] = mkc(0.f, -s0*c1);
    s[3] = mkc(-s0*s1, 0.f);
    // INPUT_LAYER
    fraud_layer(s, 0.7f, 0.3f,  0.5f,-0.4f,  0.6f,0.2f, 0.8f,-0.1f,  0.4f,0.1f, 0.5f,0.3f,  0.2f,-0.3f);
    // LAYERS[0]
    fraud_layer(s, 0.9f,-0.2f,  0.3f, 0.6f,  0.5f,0.4f,-0.7f, 0.2f,  0.6f,-0.2f,-0.3f,0.5f, 0.4f, 0.1f);
    // LAYERS[1]
    fraud_layer(s,-0.5f, 0.8f, -0.6f, 0.2f,  0.3f,-0.3f,0.9f, 0.5f,  0.2f, 0.6f, 0.7f,-0.4f,-0.5f, 0.3f);
    float p0 = s[0].x*s[0].x + s[0].y*s[0].y;
    float p1 = s[1].x*s[1].x + s[1].y*s[1].y;
    float p2 = s[2].x*s[2].x + s[2].y*s[2].y;
    float p3 = s[3].x*s[3].x + s[3].y*s[3].y;
    float z0 = p0 + p1 - p2 - p3;
    float z1 = p0 - p1 + p2 - p3;
    const float INV2PI = 0.15915494309189535f;
    #pragma unroll
    for (int l = 0; l < 16; ++l){
        int g = l >> 2, w = l & 3;
        const float* wr = Wg + (g*4 + w)*6;
        float v = (wr[0]*z0 + wr[1]*z1 + bg[g*4+w] + theta[g*4+w]) * INV2PI;
        preX[l*SEQ + t] = v;   // coalesced per l
    }
}

// ---------------- K2: serial qLSTM scan, 1 wave, 16 lanes, DPP cross-lane ----------------
#define DPP_F(dst, srcv, ctrl) \
    dst = __int_as_float(__builtin_amdgcn_update_dpp(0, __float_as_int(srcv), (ctrl), 0xF, 0xF, false))

__global__ __launch_bounds__(64, 1) void k2_scan(
        const float* __restrict__ Wg, const float* __restrict__ preX,
        float* __restrict__ hs){
    const int lane = threadIdx.x;
    if (lane >= 16) return;
    const int q = lane >> 2, w = lane & 3;
    const float INV2PI = 0.15915494309189535f;
    const float LOG2E  = 1.4426950408889634f;
    const float* wr = Wg + lane*6;
    const float Wh0 = wr[2]*INV2PI, Wh1 = wr[3]*INV2PI, Wh2 = wr[4]*INV2PI, Wh3 = wr[5]*INV2PI;
    const bool isG  = (q == 2);
    const float kMul = isG ? (-2.0f*LOG2E) : (-LOG2E);
    const float aMul = isG ? 2.0f : 1.0f;
    const float aAdd = isG ? -1.0f : 0.0f;
    const bool bq1 = (q & 1) != 0, bq2 = (q & 2) != 0;
    const bool bmid = (q == 1) || (q == 2);
    const bool w_is0 = (w == 0), w_is1 = (w == 1), w_is2 = (w == 2);
    const bool doStore = (q == 0);

    float cx = 0.0f, h0 = 0.0f, h1 = 0.0f, h2 = 0.0f, h3 = 0.0f;
    const float4* row = reinterpret_cast<const float4*>(preX + lane*SEQ);
    float4 bufA = row[0], bufB = row[1], bufC = row[2];

    for (int c = 0; c < SEQ/4; ++c){
        float4 cur = bufA; bufA = bufB; bufB = bufC;
        bufC = (c + 3 < SEQ/4) ? row[c + 3] : make_float4(0.f, 0.f, 0.f, 0.f);
        #pragma unroll
        for (int k = 0; k < 4; ++k){
            float px = (k==0) ? cur.x : (k==1) ? cur.y : (k==2) ? cur.z : cur.w;
            // pre (already includes bias+theta and 1/2pi scale): tree matvec over h
            float m3 = Wh3*h3;
            float a1 = fmaf(Wh0, h0, px);
            float a2 = fmaf(Wh2, h2, m3);
            float a3 = fmaf(Wh1, h1, a1);
            float pre = a3 + a2;
            // C = cos(2*pi*pre)
            float u = __builtin_amdgcn_fractf(pre);
            float C = __builtin_amdgcn_cosf(u);
            // intra-quad (wire) butterfly products: v_k = C[lane ^ k]
            float v1, v2, v3;
            DPP_F(v1, C, 0xB1);   // quad_perm [1,0,3,2]
            DPP_F(v2, C, 0x4E);   // quad_perm [2,3,0,1]
            DPP_F(v3, C, 0x1B);   // quad_perm [3,2,1,0]
            float ta  = v2*v3;
            float p01 = C*v1;
            float sA = w_is0 ? v1 : (w_is2 ? C : p01);
            float zz = w_is1 ? sA : sA*ta;   // z in [-1,1]
            // activation: sigma(z) or tanh(z) via exp2
            float e = __builtin_amdgcn_exp2f(zz * kMul);
            float r = __builtin_amdgcn_rcpf(1.0f + e);
            float A = fmaf(aMul, r, aAdd);
            // cross-quad xor gathers within the 16-lane row:
            float V8, tH, tF, V4, V12;
            DPP_F(V8, A, 0x128);      // row_ror:8  == lane ^ 8
            DPP_F(tH, A, 0x141);      // row_half_mirror == lane ^ 7
            DPP_F(tF, A, 0x140);      // row_mirror      == lane ^ 15
            DPP_F(V4,  tH, 0x1B);     // ^7 then ^3 -> lane ^ 4
            DPP_F(V12, tF, 0x1B);     // ^15 then ^3 -> lane ^ 12
            // gate-m value lives in V_{4*(q^m)} (V0 = A)
            float pa = V4*V8;
            float pb = A*V12;
            float P  = bmid ? pb : pa;                 // i * g
            float t1 = bq1 ? V4 : A;
            float t2 = bq1 ? V12 : V8;
            float A0 = bq2 ? t2 : t1;                  // f
            float u1 = bq1 ? V8 : V12;
            float u2 = bq1 ? A : V4;
            float A3 = bq2 ? u2 : u1;                  // o
            cx = fmaf(A0, cx, P);
            // tanh(cx) = 1 - 2/(1+e^{2 cx})
            float e2 = __builtin_amdgcn_exp2f(cx * (2.0f*LOG2E));
            float r2 = __builtin_amdgcn_rcpf(1.0f + e2);
            float th = fmaf(-2.0f, r2, 1.0f);
            float hme = A3 * th;                       // h_{w} (identical in all quads)
            if (doStore) hs[(c*4 + k)*4 + w] = hme;
            // broadcast h0..h3 within quad for next matvec
            DPP_F(h0, hme, 0x00);
            DPP_F(h1, hme, 0x55);
            DPP_F(h2, hme, 0xAA);
            DPP_F(h3, hme, 0xFF);
        }
    }
}

// ---------------- K3: logits + log_softmax, one wave per row ----------------
__global__ __launch_bounds__(256) void k3_tags(
        const float* __restrict__ hs, const float* __restrict__ Wtag,
        const float* __restrict__ btag, float* __restrict__ out){
    int wid = threadIdx.x >> 6, lane = threadIdx.x & 63;
    int rowI = blockIdx.x*4 + wid;
    float4 h = *reinterpret_cast<const float4*>(hs + rowI*4);
    int c0 = lane, c1 = lane + 64;
    float4 w0v = *reinterpret_cast<const float4*>(Wtag + c0*4);
    float4 w1v = *reinterpret_cast<const float4*>(Wtag + c1*4);
    float l0 = fmaf(h.x, w0v.x, fmaf(h.y, w0v.y, fmaf(h.z, w0v.z, fmaf(h.w, w0v.w, btag[c0]))));
    float l1 = fmaf(h.x, w1v.x, fmaf(h.y, w1v.y, fmaf(h.z, w1v.z, fmaf(h.w, w1v.w, btag[c1]))));
    float mx = fmaxf(l0, l1);
    #pragma unroll
    for (int m = 32; m >= 1; m >>= 1) mx = fmaxf(mx, __shfl_xor(mx, m, 64));
    const float K = 1.4426950408889634f, LN2 = 0.6931471805599453f;
    float e0 = __builtin_amdgcn_exp2f((l0 - mx)*K);
    float e1 = __builtin_amdgcn_exp2f((l1 - mx)*K);
    float s = e0 + e1;
    #pragma unroll
    for (int m = 32; m >= 1; m >>= 1) s += __shfl_xor(s, m, 64);
    float lse = __builtin_amdgcn_logf(s) * LN2;
    out[rowI*TAGS + c0] = l0 - mx - lse;
    out[rowI*TAGS + c1] = l1 - mx - lse;
}

extern "C" void kernel_launch(void* const* d_in, const int* in_sizes, int n_in,
                              void* d_out, int out_size, void* d_ws, size_t ws_size,
                              hipStream_t stream) {
    const float* emb   = (const float*)d_in[0];
    const float* Wg    = (const float*)d_in[1];
    const float* bg    = (const float*)d_in[2];
    const float* theta = (const float*)d_in[3];
    const float* Wtag  = (const float*)d_in[4];
    const float* btag  = (const float*)d_in[5];
    const int*   sent  = (const int*)d_in[6];
    float* out = (float*)d_out;

    float* preX = (float*)d_ws;                 // [16][SEQ]  = 512 KB
    float* hs   = (float*)d_ws + 16*SEQ;        // [SEQ][4]   = 128 KB

    k1_feats_pre<<<SEQ/256, 256, 0, stream>>>(emb, Wg, bg, theta, sent, preX);
    k2_scan<<<1, 64, 0, stream>>>(Wg, preX, hs);
    k3_tags<<<SEQ/4, 256, 0, stream>>>(hs, Wtag, btag, out);
}

// Round 2
// 29.902 us; speedup vs baseline: 50.1435x; 50.1435x over previous
//
#include <hip/hip_runtime.h>
#include <math.h>
#include <complex>

#define SEQ 8192
#define TAGS 128
#define ROWSTRIDE (SEQ + 64)      // 64-entry warmup pad in front of each row
#define CH_OUT 32                 // outputs per chain
#define WARM 64                   // warmup steps (washout: 0.731^64 ~ 2e-9)
#define NCHAIN (SEQ / CH_OUT)     // 256 chains
#define NSTEP (WARM + CH_OUT)     // 96 serial steps per chain
#define NCHUNK (NSTEP / 4)        // 24 float4 chunks

// ---------------- host: fold constant photonic circuit into one 4x4 ----------------
typedef std::complex<double> cd;

static void apply_pair(cd M[4][4], const cd U00, const cd U01, const cd U10, const cd U11,
                       int a, int b){
    for (int j = 0; j < 4; ++j){
        cd ra = M[a][j], rb = M[b][j];
        M[a][j] = U00*ra + U01*rb;
        M[b][j] = U10*ra + U11*rb;
    }
}
static void rx_h(cd M[4][4], double th, int w){
    double c = cos(0.5*th), s = sin(0.5*th);
    cd u00(c,0), u01(0,-s), u10(0,-s), u11(c,0);
    if (w == 0){ apply_pair(M,u00,u01,u10,u11,0,2); apply_pair(M,u00,u01,u10,u11,1,3); }
    else       { apply_pair(M,u00,u01,u10,u11,0,1); apply_pair(M,u00,u01,u10,u11,2,3); }
}
static void rot2_h(cd M[4][4], double r, double phi, int w){
    double cr = cos(r), sr = sin(r);
    cd ep(cos(phi), sin(phi)), em(cos(phi), -sin(phi));
    cd u00(cr,0), u01 = -ep*sr, u10 = em*sr, u11(cr,0);
    if (w == 0){ apply_pair(M,u00,u01,u10,u11,0,2); apply_pair(M,u00,u01,u10,u11,1,3); }
    else       { apply_pair(M,u00,u01,u10,u11,0,1); apply_pair(M,u00,u01,u10,u11,2,3); }
}
static void phase_h(cd M[4][4], double k, int w){
    cd e(cos(k), sin(k));
    cd one(1,0), zero(0,0);
    if (w == 0){ apply_pair(M,one,zero,zero,e,0,2); apply_pair(M,one,zero,zero,e,1,3); }
    else       { apply_pair(M,one,zero,zero,e,0,1); apply_pair(M,one,zero,zero,e,2,3); }
}
static void bs_h(cd M[4][4], double th, double phi){
    double ct = cos(th), st = sin(th);
    cd ep(cos(phi), sin(phi)), em(cos(phi), -sin(phi));
    apply_pair(M, cd(ct,0), -ep*st, em*st, cd(ct,0), 1, 2);
}
static void fraud_h(cd M[4][4], double bst, double bsp, double ph0, double ph1,
                    double sr0, double sp0, double sr1, double sp1,
                    double dr0, double dp0, double dr1, double dp1,
                    double k0, double k1){
    bs_h(M, bst, bsp);
    rx_h(M, ph0, 0); rx_h(M, ph1, 1);
    rot2_h(M, sr0, sp0, 0); rot2_h(M, sr1, sp1, 1);
    bs_h(M, bst, bsp);
    rx_h(M, ph0, 0); rx_h(M, ph1, 1);
    rot2_h(M, dr0, dp0, 0); rot2_h(M, dr1, dp1, 1);
    phase_h(M, k0, 0); phase_h(M, k1, 1);
}

struct MArg { float mr[16]; float mi[16]; };

// ---------------- K1: photonic feats (as one matvec) + preX + pad ----------------
__global__ __launch_bounds__(256) void k1_feats_pre(
        const float* __restrict__ emb, const float* __restrict__ Wg,
        const float* __restrict__ bg, const float* __restrict__ theta,
        const int* __restrict__ sent, float* __restrict__ preX, MArg M){
    int t = blockIdx.x * blockDim.x + threadIdx.x;
    if (t >= SEQ) return;
    if (t < WARM){
        #pragma unroll
        for (int l = 0; l < 16; ++l) preX[l*ROWSTRIDE + t] = 0.25f;
    }
    int idx = sent[t];
    float x0 = emb[idx*2 + 0], x1 = emb[idx*2 + 1];
    float c0 = cosf(0.5f*x0), s0 = sinf(0.5f*x0);
    float c1 = cosf(0.5f*x1), s1 = sinf(0.5f*x1);
    // psi0 = x + i*y, x = (c0c1, 0, 0, -s0s1), y = (0, -c0s1, -s0c1, 0)
    float xc = c0*c1, xs = -s0*s1, ya = -c0*s1, yb = -s0*c1;
    float p[4];
    #pragma unroll
    for (int i = 0; i < 4; ++i){
        float re =  M.mr[i*4+0]*xc + M.mr[i*4+3]*xs - M.mi[i*4+1]*ya - M.mi[i*4+2]*yb;
        float im =  M.mi[i*4+0]*xc + M.mi[i*4+3]*xs + M.mr[i*4+1]*ya + M.mr[i*4+2]*yb;
        p[i] = re*re + im*im;
    }
    float z0 = p[0] + p[1] - p[2] - p[3];
    float z1 = p[0] - p[1] + p[2] - p[3];
    const float INV2PI = 0.15915494309189535f;
    #pragma unroll
    for (int l = 0; l < 16; ++l){
        const float* wr = Wg + l*6;
        float v = (wr[0]*z0 + wr[1]*z1 + bg[l] + theta[l]) * INV2PI;
        preX[l*ROWSTRIDE + WARM + t] = v;
    }
}

// ---------------- K2: chunked qLSTM scan, 4 chains/wave, DPP cross-lane ----------------
#define DPP_F(dst, srcv, ctrl) \
    dst = __int_as_float(__builtin_amdgcn_update_dpp(0, __float_as_int(srcv), (ctrl), 0xF, 0xF, false))

__global__ __launch_bounds__(64, 1) void k2_scan(
        const float* __restrict__ Wg, const float* __restrict__ preX,
        float* __restrict__ hs){
    const int lane = threadIdx.x;
    const int sub = lane & 15;             // lane within chain
    const int chain = blockIdx.x*4 + (lane >> 4);
    const int q = sub >> 2, w = sub & 3;
    const float INV2PI = 0.15915494309189535f;
    const float LOG2E  = 1.4426950408889634f;
    const float* wr = Wg + sub*6;
    const float Wh0 = wr[2]*INV2PI, Wh1 = wr[3]*INV2PI, Wh2 = wr[4]*INV2PI, Wh3 = wr[5]*INV2PI;
    const bool isG  = (q == 2);
    const float kMul = isG ? (-2.0f*LOG2E) : (-LOG2E);
    const float aMul = isG ? 2.0f : 1.0f;
    const float aAdd = isG ? -1.0f : 0.0f;
    const bool bq1 = (q & 1) != 0, bq2 = (q & 2) != 0;
    const bool bmid = (q == 1) || (q == 2);
    const bool w_is0 = (w == 0), w_is1 = (w == 1), w_is2 = (w == 2);
    const bool doStore = (q == 0);
    const int tOutBase = chain*CH_OUT - WARM;   // t for step i: tOutBase + i

    float cx = 0.0f, h0 = 0.0f, h1 = 0.0f, h2 = 0.0f, h3 = 0.0f;
    const float4* rp = reinterpret_cast<const float4*>(preX + sub*ROWSTRIDE + chain*CH_OUT);
    float4 bufA = rp[0], bufB = rp[1], bufC = rp[2];

    for (int c = 0; c < NCHUNK; ++c){
        float4 cur = bufA; bufA = bufB; bufB = bufC;
        bufC = (c + 3 < NCHUNK) ? rp[c + 3] : make_float4(0.f, 0.f, 0.f, 0.f);
        #pragma unroll
        for (int k = 0; k < 4; ++k){
            float px = (k==0) ? cur.x : (k==1) ? cur.y : (k==2) ? cur.z : cur.w;
            // pre (includes bias+theta and 1/2pi): tree matvec over h
            float m3 = Wh3*h3;
            float a1 = fmaf(Wh0, h0, px);
            float a2 = fmaf(Wh2, h2, m3);
            float a3 = fmaf(Wh1, h1, a1);
            float pre = a3 + a2;
            // C = cos(2*pi*pre)
            float u = __builtin_amdgcn_fractf(pre);
            float C = __builtin_amdgcn_cosf(u);
            // intra-quad (wire) butterfly products: v_k = C[lane ^ k]
            float v1, v2, v3;
            DPP_F(v1, C, 0xB1);   // quad_perm [1,0,3,2]
            DPP_F(v2, C, 0x4E);   // quad_perm [2,3,0,1]
            DPP_F(v3, C, 0x1B);   // quad_perm [3,2,1,0]
            float ta  = v2*v3;
            float p01 = C*v1;
            float sA = w_is0 ? v1 : (w_is2 ? C : p01);
            float zz = w_is1 ? sA : sA*ta;   // z in [-1,1]
            // activation: sigma(z) or tanh(z) via exp2
            float e = __builtin_amdgcn_exp2f(zz * kMul);
            float r = __builtin_amdgcn_rcpf(1.0f + e);
            float A = fmaf(aMul, r, aAdd);
            // cross-quad xor gathers within the 16-lane row
            float V8, tH, tF, V4, V12;
            DPP_F(V8, A, 0x128);      // row_ror:8  == lane ^ 8
            DPP_F(tH, A, 0x141);      // row_half_mirror == lane ^ 7
            DPP_F(tF, A, 0x140);      // row_mirror      == lane ^ 15
            DPP_F(V4,  tH, 0x1B);     // ^7 then ^3 -> lane ^ 4
            DPP_F(V12, tF, 0x1B);     // ^15 then ^3 -> lane ^ 12
            float pa = V4*V8;
            float pb = A*V12;
            float P  = bmid ? pb : pa;                 // i * g
            float t1 = bq1 ? V4 : A;
            float t2 = bq1 ? V12 : V8;
            float A0 = bq2 ? t2 : t1;                  // f
            float u1 = bq1 ? V8 : V12;
            float u2 = bq1 ? A : V4;
            float A3 = bq2 ? u2 : u1;                  // o
            cx = fmaf(A0, cx, P);
            // tanh(cx) = 1 - 2/(1+e^{2 cx})
            float e2 = __builtin_amdgcn_exp2f(cx * (2.0f*LOG2E));
            float r2 = __builtin_amdgcn_rcpf(1.0f + e2);
            float th = fmaf(-2.0f, r2, 1.0f);
            float hme = A3 * th;                       // h_w (same in all quads)
            if (c >= WARM/4 && doStore) hs[(tOutBase + c*4 + k)*4 + w] = hme;
            // broadcast h0..h3 within quad for next matvec
            DPP_F(h0, hme, 0x00);
            DPP_F(h1, hme, 0x55);
            DPP_F(h2, hme, 0xAA);
            DPP_F(h3, hme, 0xFF);
        }
    }
}

// ---------------- K3: logits + log_softmax, one wave per row ----------------
__global__ __launch_bounds__(256) void k3_tags(
        const float* __restrict__ hs, const float* __restrict__ Wtag,
        const float* __restrict__ btag, float* __restrict__ out){
    int wid = threadIdx.x >> 6, lane = threadIdx.x & 63;
    int rowI = blockIdx.x*4 + wid;
    float4 h = *reinterpret_cast<const float4*>(hs + rowI*4);
    int c0 = lane, c1 = lane + 64;
    float4 w0v = *reinterpret_cast<const float4*>(Wtag + c0*4);
    float4 w1v = *reinterpret_cast<const float4*>(Wtag + c1*4);
    float l0 = fmaf(h.x, w0v.x, fmaf(h.y, w0v.y, fmaf(h.z, w0v.z, fmaf(h.w, w0v.w, btag[c0]))));
    float l1 = fmaf(h.x, w1v.x, fmaf(h.y, w1v.y, fmaf(h.z, w1v.z, fmaf(h.w, w1v.w, btag[c1]))));
    float mx = fmaxf(l0, l1);
    #pragma unroll
    for (int m = 32; m >= 1; m >>= 1) mx = fmaxf(mx, __shfl_xor(mx, m, 64));
    const float K = 1.4426950408889634f, LN2 = 0.6931471805599453f;
    float e0 = __builtin_amdgcn_exp2f((l0 - mx)*K);
    float e1 = __builtin_amdgcn_exp2f((l1 - mx)*K);
    float s = e0 + e1;
    #pragma unroll
    for (int m = 32; m >= 1; m >>= 1) s += __shfl_xor(s, m, 64);
    float lse = __builtin_amdgcn_logf(s) * LN2;
    out[rowI*TAGS + c0] = l0 - mx - lse;
    out[rowI*TAGS + c1] = l1 - mx - lse;
}

extern "C" void kernel_launch(void* const* d_in, const int* in_sizes, int n_in,
                              void* d_out, int out_size, void* d_ws, size_t ws_size,
                              hipStream_t stream) {
    const float* emb   = (const float*)d_in[0];
    const float* Wg    = (const float*)d_in[1];
    const float* bg    = (const float*)d_in[2];
    const float* theta = (const float*)d_in[3];
    const float* Wtag  = (const float*)d_in[4];
    const float* btag  = (const float*)d_in[5];
    const int*   sent  = (const int*)d_in[6];
    float* out = (float*)d_out;

    float* preX = (float*)d_ws;                      // [16][ROWSTRIDE]
    float* hs   = (float*)d_ws + 16*ROWSTRIDE;       // [SEQ][4]

    // Fold the constant photonic circuit into a single 4x4 complex matrix (host, fp64)
    cd M[4][4];
    for (int i = 0; i < 4; ++i) for (int j = 0; j < 4; ++j) M[i][j] = (i==j) ? cd(1,0) : cd(0,0);
    fraud_h(M, 0.7, 0.3,  0.5,-0.4,  0.6,0.2, 0.8,-0.1,  0.4,0.1, 0.5,0.3,  0.2,-0.3);
    fraud_h(M, 0.9,-0.2,  0.3, 0.6,  0.5,0.4,-0.7, 0.2,  0.6,-0.2,-0.3,0.5, 0.4, 0.1);
    fraud_h(M,-0.5, 0.8, -0.6, 0.2,  0.3,-0.3,0.9, 0.5,  0.2, 0.6, 0.7,-0.4,-0.5, 0.3);
    MArg ma;
    for (int i = 0; i < 16; ++i){ ma.mr[i] = (float)M[i/4][i%4].real(); ma.mi[i] = (float)M[i/4][i%4].imag(); }

    k1_feats_pre<<<SEQ/256, 256, 0, stream>>>(emb, Wg, bg, theta, sent, preX, ma);
    k2_scan<<<NCHAIN/4, 64, 0, stream>>>(Wg, preX, hs);
    k3_tags<<<SEQ/4, 256, 0, stream>>>(hs, Wtag, btag, out);
}

// Round 3
// 18.868 us; speedup vs baseline: 79.4673x; 1.5848x over previous
//
#include <hip/hip_runtime.h>
#include <math.h>
#include <complex>

#define SEQ 8192
#define TAGS 128
#define CH_OUT 8                  // outputs per chain
#define WARM 32                   // warmup steps (f <= 0.731 => washout ~4e-5)
#define NSTEP (WARM + CH_OUT)     // 40 serial steps
#define NCHUNK (NSTEP / 4)        // 10
#define ROWS_PER_BLK 32           // 4 chains * CH_OUT
#define LDSROW 68                 // padded px row stride (floats)

// ---------------- host: fold constant photonic circuit into one 4x4 ----------------
typedef std::complex<double> cd;

static void apply_pair(cd M[4][4], const cd U00, const cd U01, const cd U10, const cd U11,
                       int a, int b){
    for (int j = 0; j < 4; ++j){
        cd ra = M[a][j], rb = M[b][j];
        M[a][j] = U00*ra + U01*rb;
        M[b][j] = U10*ra + U11*rb;
    }
}
static void rx_h(cd M[4][4], double th, int w){
    double c = cos(0.5*th), s = sin(0.5*th);
    cd u00(c,0), u01(0,-s), u10(0,-s), u11(c,0);
    if (w == 0){ apply_pair(M,u00,u01,u10,u11,0,2); apply_pair(M,u00,u01,u10,u11,1,3); }
    else       { apply_pair(M,u00,u01,u10,u11,0,1); apply_pair(M,u00,u01,u10,u11,2,3); }
}
static void rot2_h(cd M[4][4], double r, double phi, int w){
    double cr = cos(r), sr = sin(r);
    cd ep(cos(phi), sin(phi)), em(cos(phi), -sin(phi));
    cd u00(cr,0), u01 = -ep*sr, u10 = em*sr, u11(cr,0);
    if (w == 0){ apply_pair(M,u00,u01,u10,u11,0,2); apply_pair(M,u00,u01,u10,u11,1,3); }
    else       { apply_pair(M,u00,u01,u10,u11,0,1); apply_pair(M,u00,u01,u10,u11,2,3); }
}
static void phase_h(cd M[4][4], double k, int w){
    cd e(cos(k), sin(k));
    cd one(1,0), zero(0,0);
    if (w == 0){ apply_pair(M,one,zero,zero,e,0,2); apply_pair(M,one,zero,zero,e,1,3); }
    else       { apply_pair(M,one,zero,zero,e,0,1); apply_pair(M,one,zero,zero,e,2,3); }
}
static void bs_h(cd M[4][4], double th, double phi){
    double ct = cos(th), st = sin(th);
    cd ep(cos(phi), sin(phi)), em(cos(phi), -sin(phi));
    apply_pair(M, cd(ct,0), -ep*st, em*st, cd(ct,0), 1, 2);
}
static void fraud_h(cd M[4][4], double bst, double bsp, double ph0, double ph1,
                    double sr0, double sp0, double sr1, double sp1,
                    double dr0, double dp0, double dr1, double dp1,
                    double k0, double k1){
    bs_h(M, bst, bsp);
    rx_h(M, ph0, 0); rx_h(M, ph1, 1);
    rot2_h(M, sr0, sp0, 0); rot2_h(M, sr1, sp1, 1);
    bs_h(M, bst, bsp);
    rx_h(M, ph0, 0); rx_h(M, ph1, 1);
    rot2_h(M, dr0, dp0, 0); rot2_h(M, dr1, dp1, 1);
    phase_h(M, k0, 0); phase_h(M, k1, 1);
}

struct MArg { float mr[16]; float mi[16]; };

#define DPP_F(dst, srcv, ctrl) \
    dst = __int_as_float(__builtin_amdgcn_update_dpp(0, __float_as_int(srcv), (ctrl), 0xF, 0xF, false))

// ---------------- fully fused kernel: 1 block = 4 chains = 32 output rows ----------------
__global__ __launch_bounds__(64, 1) void k_fused(
        const float* __restrict__ emb, const float* __restrict__ Wg,
        const float* __restrict__ bg, const float* __restrict__ theta,
        const float* __restrict__ Wtag, const float* __restrict__ btag,
        const int* __restrict__ sent, float* __restrict__ out, MArg M){
    __shared__ float spx[16 * LDSROW];
    __shared__ float hrow[ROWS_PER_BLK * 4];

    const int lane = threadIdx.x;
    const int sub = lane & 15, d = lane >> 4;
    const int q = sub >> 2, w = sub & 3;
    const float INV2PI = 0.15915494309189535f;
    const float LOG2E  = 1.4426950408889634f;

    // ---- Phase A: this lane owns t = tbase + lane; fill px for all 16 gate-wires ----
    const int tbase = blockIdx.x * ROWS_PER_BLK - WARM;
    const int t = tbase + lane;                       // [base-32, base+32)
    const bool padT = (t < 0);
    const int idx = sent[padT ? 0 : t];
    {
        float x0 = emb[idx*2 + 0], x1 = emb[idx*2 + 1];
        float c0 = cosf(0.5f*x0), s0 = sinf(0.5f*x0);
        float c1 = cosf(0.5f*x1), s1 = sinf(0.5f*x1);
        // psi0 = x + i*y: x = (c0c1, 0, 0, -s0s1), y = (0, -c0s1, -s0c1, 0)
        float xc = c0*c1, xs = -s0*s1, ya = -c0*s1, yb = -s0*c1;
        float p[4];
        #pragma unroll
        for (int i = 0; i < 4; ++i){
            float re = M.mr[i*4+0]*xc + M.mr[i*4+3]*xs - M.mi[i*4+1]*ya - M.mi[i*4+2]*yb;
            float im = M.mi[i*4+0]*xc + M.mi[i*4+3]*xs + M.mr[i*4+1]*ya + M.mr[i*4+2]*yb;
            p[i] = re*re + im*im;
        }
        float z0 = p[0] + p[1] - p[2] - p[3];
        float z1 = p[0] - p[1] + p[2] - p[3];
        #pragma unroll
        for (int l = 0; l < 16; ++l){
            float v = (Wg[l*6]*z0 + Wg[l*6+1]*z1 + bg[l] + theta[l]) * INV2PI;
            spx[l*LDSROW + lane] = padT ? 0.25f : v;   // pad -> C=cos(pi/2)=0 -> state stays 0
        }
    }
    __syncthreads();

    // ---- Phase B: 40-step scan; px preloaded to registers (fully unrolled => static idx) ----
    const float* wr = Wg + sub*6;
    const float Wh0 = wr[2]*INV2PI, Wh1 = wr[3]*INV2PI, Wh2 = wr[4]*INV2PI, Wh3 = wr[5]*INV2PI;
    const bool isG  = (q == 2);
    const float kMul = isG ? (-2.0f*LOG2E) : (-LOG2E);
    const float aMul = isG ? 2.0f : 1.0f;
    const float aAdd = isG ? -1.0f : 0.0f;
    const bool bq1 = (q & 1) != 0, bq2 = (q & 2) != 0;
    const bool bmid = (q == 1) || (q == 2);
    const bool w_is0 = (w == 0), w_is1 = (w == 1), w_is2 = (w == 2);
    const bool doStore = (q == 0);

    float4 P[NCHUNK];
    {
        const float4* prow = reinterpret_cast<const float4*>(&spx[sub*LDSROW + 8*d]);
        #pragma unroll
        for (int i = 0; i < NCHUNK; ++i) P[i] = prow[i];
    }

    float cx = 0.0f, h0 = 0.0f, h1 = 0.0f, h2 = 0.0f, h3 = 0.0f;
    #pragma unroll
    for (int c = 0; c < NCHUNK; ++c){
        float4 cur = P[c];
        #pragma unroll
        for (int k = 0; k < 4; ++k){
            float px = (k==0) ? cur.x : (k==1) ? cur.y : (k==2) ? cur.z : cur.w;
            float m3 = Wh3*h3;
            float a1 = fmaf(Wh0, h0, px);
            float a2 = fmaf(Wh2, h2, m3);
            float a3 = fmaf(Wh1, h1, a1);
            float pre = a3 + a2;
            float u = __builtin_amdgcn_fractf(pre);
            float C = __builtin_amdgcn_cosf(u);
            float v1, v2, v3;
            DPP_F(v1, C, 0xB1);   // quad_perm [1,0,3,2] : lane^1
            DPP_F(v2, C, 0x4E);   // quad_perm [2,3,0,1] : lane^2
            DPP_F(v3, C, 0x1B);   // quad_perm [3,2,1,0] : lane^3
            float ta  = v2*v3;
            float p01 = C*v1;
            float sA = w_is0 ? v1 : (w_is2 ? C : p01);
            float zz = w_is1 ? sA : sA*ta;
            float e = __builtin_amdgcn_exp2f(zz * kMul);
            float r = __builtin_amdgcn_rcpf(1.0f + e);
            float A = fmaf(aMul, r, aAdd);
            float V8, tH, tF, V4, V12;
            DPP_F(V8, A, 0x128);      // row_ror:8  == lane^8 (within 16-lane row)
            DPP_F(tH, A, 0x141);      // row_half_mirror == lane^7
            DPP_F(tF, A, 0x140);      // row_mirror      == lane^15
            DPP_F(V4,  tH, 0x1B);     // ^7 then ^3 -> lane^4
            DPP_F(V12, tF, 0x1B);     // ^15 then ^3 -> lane^12
            float pa = V4*V8;
            float pb = A*V12;
            float Pig = bmid ? pb : pa;                // i * g
            float t1 = bq1 ? V4 : A;
            float t2 = bq1 ? V12 : V8;
            float A0 = bq2 ? t2 : t1;                  // f
            float u1 = bq1 ? V8 : V12;
            float u2 = bq1 ? A : V4;
            float A3 = bq2 ? u2 : u1;                  // o
            cx = fmaf(A0, cx, Pig);
            float e2 = __builtin_amdgcn_exp2f(cx * (2.0f*LOG2E));
            float r2 = __builtin_amdgcn_rcpf(1.0f + e2);
            float th = fmaf(-2.0f, r2, 1.0f);
            float hme = A3 * th;                       // h_w (same in all quads)
            if (c >= WARM/4 && doStore)
                hrow[(d*CH_OUT + (c*4 + k) - WARM)*4 + w] = hme;
            DPP_F(h0, hme, 0x00);
            DPP_F(h1, hme, 0x55);
            DPP_F(h2, hme, 0xAA);
            DPP_F(h3, hme, 0xFF);
        }
    }
    __syncthreads();

    // ---- Phase C: logits + log_softmax for this block's 32 rows ----
    const int c0 = lane, c1 = lane + 64;
    float4 w0v = *reinterpret_cast<const float4*>(Wtag + c0*4);
    float4 w1v = *reinterpret_cast<const float4*>(Wtag + c1*4);
    float b0 = btag[c0], b1 = btag[c1];
    float* outbase = out + (size_t)blockIdx.x * ROWS_PER_BLK * TAGS;
    const float K = 1.4426950408889634f, LN2 = 0.6931471805599453f;
    #pragma unroll 4
    for (int rI = 0; rI < ROWS_PER_BLK; ++rI){
        float4 h = *reinterpret_cast<const float4*>(&hrow[rI*4]);   // LDS broadcast
        float l0 = fmaf(h.x, w0v.x, fmaf(h.y, w0v.y, fmaf(h.z, w0v.z, fmaf(h.w, w0v.w, b0))));
        float l1 = fmaf(h.x, w1v.x, fmaf(h.y, w1v.y, fmaf(h.z, w1v.z, fmaf(h.w, w1v.w, b1))));
        float mx = fmaxf(l0, l1);
        #pragma unroll
        for (int m = 32; m >= 1; m >>= 1) mx = fmaxf(mx, __shfl_xor(mx, m, 64));
        float e0 = __builtin_amdgcn_exp2f((l0 - mx)*K);
        float e1 = __builtin_amdgcn_exp2f((l1 - mx)*K);
        float s = e0 + e1;
        #pragma unroll
        for (int m = 32; m >= 1; m >>= 1) s += __shfl_xor(s, m, 64);
        float lse = __builtin_amdgcn_logf(s) * LN2;
        outbase[rI*TAGS + c0] = l0 - mx - lse;
        outbase[rI*TAGS + c1] = l1 - mx - lse;
    }
}

extern "C" void kernel_launch(void* const* d_in, const int* in_sizes, int n_in,
                              void* d_out, int out_size, void* d_ws, size_t ws_size,
                              hipStream_t stream) {
    const float* emb   = (const float*)d_in[0];
    const float* Wg    = (const float*)d_in[1];
    const float* bg    = (const float*)d_in[2];
    const float* theta = (const float*)d_in[3];
    const float* Wtag  = (const float*)d_in[4];
    const float* btag  = (const float*)d_in[5];
    const int*   sent  = (const int*)d_in[6];
    float* out = (float*)d_out;

    // Fold the constant photonic circuit into a single 4x4 complex matrix (host, fp64)
    cd M[4][4];
    for (int i = 0; i < 4; ++i) for (int j = 0; j < 4; ++j) M[i][j] = (i==j) ? cd(1,0) : cd(0,0);
    fraud_h(M, 0.7, 0.3,  0.5,-0.4,  0.6,0.2, 0.8,-0.1,  0.4,0.1, 0.5,0.3,  0.2,-0.3);
    fraud_h(M, 0.9,-0.2,  0.3, 0.6,  0.5,0.4,-0.7, 0.2,  0.6,-0.2,-0.3,0.5, 0.4, 0.1);
    fraud_h(M,-0.5, 0.8, -0.6, 0.2,  0.3,-0.3,0.9, 0.5,  0.2, 0.6, 0.7,-0.4,-0.5, 0.3);
    MArg ma;
    for (int i = 0; i < 16; ++i){ ma.mr[i] = (float)M[i/4][i%4].real(); ma.mi[i] = (float)M[i/4][i%4].imag(); }

    k_fused<<<SEQ/ROWS_PER_BLK, 64, 0, stream>>>(emb, Wg, bg, theta, Wtag, btag, sent, out, ma);
}

// Round 4
// 12.058 us; speedup vs baseline: 124.3428x; 1.5647x over previous
//
#include <hip/hip_runtime.h>
#include <math.h>
#include <complex>

#define SEQ 8192
#define TAGS 128
#define CH_OUT 8                  // outputs per chain
#define WARM 16                   // warmup steps (contraction ~0.6/step => residual ~3e-4)
#define NSTEP (WARM + CH_OUT)     // 24 serial steps
#define NCHUNK (NSTEP / 4)        // 6
#define ROWS_PER_BLK 32           // 4 chains * CH_OUT
#define TRANGE (3*CH_OUT + NSTEP) // 48 t-values needed per block
#define LDSROW 52                 // padded px row stride (floats, mult of 4)

// ---------------- host: fold constant photonic circuit into one 4x4 ----------------
typedef std::complex<double> cd;

static void apply_pair(cd M[4][4], const cd U00, const cd U01, const cd U10, const cd U11,
                       int a, int b){
    for (int j = 0; j < 4; ++j){
        cd ra = M[a][j], rb = M[b][j];
        M[a][j] = U00*ra + U01*rb;
        M[b][j] = U10*ra + U11*rb;
    }
}
static void rx_h(cd M[4][4], double th, int w){
    double c = cos(0.5*th), s = sin(0.5*th);
    cd u00(c,0), u01(0,-s), u10(0,-s), u11(c,0);
    if (w == 0){ apply_pair(M,u00,u01,u10,u11,0,2); apply_pair(M,u00,u01,u10,u11,1,3); }
    else       { apply_pair(M,u00,u01,u10,u11,0,1); apply_pair(M,u00,u01,u10,u11,2,3); }
}
static void rot2_h(cd M[4][4], double r, double phi, int w){
    double cr = cos(r), sr = sin(r);
    cd ep(cos(phi), sin(phi)), em(cos(phi), -sin(phi));
    cd u00(cr,0), u01 = -ep*sr, u10 = em*sr, u11(cr,0);
    if (w == 0){ apply_pair(M,u00,u01,u10,u11,0,2); apply_pair(M,u00,u01,u10,u11,1,3); }
    else       { apply_pair(M,u00,u01,u10,u11,0,1); apply_pair(M,u00,u01,u10,u11,2,3); }
}
static void phase_h(cd M[4][4], double k, int w){
    cd e(cos(k), sin(k));
    cd one(1,0), zero(0,0);
    if (w == 0){ apply_pair(M,one,zero,zero,e,0,2); apply_pair(M,one,zero,zero,e,1,3); }
    else       { apply_pair(M,one,zero,zero,e,0,1); apply_pair(M,one,zero,zero,e,2,3); }
}
static void bs_h(cd M[4][4], double th, double phi){
    double ct = cos(th), st = sin(th);
    cd ep(cos(phi), sin(phi)), em(cos(phi), -sin(phi));
    apply_pair(M, cd(ct,0), -ep*st, em*st, cd(ct,0), 1, 2);
}
static void fraud_h(cd M[4][4], double bst, double bsp, double ph0, double ph1,
                    double sr0, double sp0, double sr1, double sp1,
                    double dr0, double dp0, double dr1, double dp1,
                    double k0, double k1){
    bs_h(M, bst, bsp);
    rx_h(M, ph0, 0); rx_h(M, ph1, 1);
    rot2_h(M, sr0, sp0, 0); rot2_h(M, sr1, sp1, 1);
    bs_h(M, bst, bsp);
    rx_h(M, ph0, 0); rx_h(M, ph1, 1);
    rot2_h(M, dr0, dp0, 0); rot2_h(M, dr1, dp1, 1);
    phase_h(M, k0, 0); phase_h(M, k1, 1);
}

struct MArg { float mr[16]; float mi[16]; };

#define DPP_F(dst, srcv, ctrl) \
    dst = __int_as_float(__builtin_amdgcn_update_dpp(0, __float_as_int(srcv), (ctrl), 0xF, 0xF, false))

// ---------------- fully fused kernel: 1 block = 4 chains = 32 output rows ----------------
__global__ __launch_bounds__(64, 1) void k_fused(
        const float* __restrict__ emb, const float* __restrict__ Wg,
        const float* __restrict__ bg, const float* __restrict__ theta,
        const float* __restrict__ Wtag, const float* __restrict__ btag,
        const int* __restrict__ sent, float* __restrict__ out, MArg M){
    __shared__ float spx[16 * LDSROW];
    __shared__ float hrow[ROWS_PER_BLK * 4];

    const int lane = threadIdx.x;
    const int sub = lane & 15, d = lane >> 4;
    const int q = sub >> 2, w = sub & 3;
    const float INV2PI = 0.15915494309189535f;
    const float INV4PI = 0.07957747154594767f;
    const float LOG2E  = 1.4426950408889634f;

    // ---- Phase A: lane < TRANGE owns t = tbase + lane; fill px for all 16 gate-wires ----
    const int tbase = blockIdx.x * ROWS_PER_BLK - WARM;
    if (lane < TRANGE){
        const int t = tbase + lane;
        const bool padT = (t < 0);
        const int idx = sent[padT ? 0 : t];
        float x0 = emb[idx*2 + 0], x1 = emb[idx*2 + 1];
        // cos(x/2), sin(x/2) via v_cos/v_sin (revolutions)
        float u0 = __builtin_amdgcn_fractf(x0 * INV4PI);
        float u1 = __builtin_amdgcn_fractf(x1 * INV4PI);
        float c0 = __builtin_amdgcn_cosf(u0), s0 = __builtin_amdgcn_sinf(u0);
        float c1 = __builtin_amdgcn_cosf(u1), s1 = __builtin_amdgcn_sinf(u1);
        // psi0 = x + i*y: x = (c0c1, 0, 0, -s0s1), y = (0, -c0s1, -s0c1, 0)
        float xc = c0*c1, xs = -s0*s1, ya = -c0*s1, yb = -s0*c1;
        float p[4];
        #pragma unroll
        for (int i = 0; i < 4; ++i){
            float re = M.mr[i*4+0]*xc + M.mr[i*4+3]*xs - M.mi[i*4+1]*ya - M.mi[i*4+2]*yb;
            float im = M.mi[i*4+0]*xc + M.mi[i*4+3]*xs + M.mr[i*4+1]*ya + M.mr[i*4+2]*yb;
            p[i] = re*re + im*im;
        }
        float z0 = p[0] + p[1] - p[2] - p[3];
        float z1 = p[0] - p[1] + p[2] - p[3];
        #pragma unroll
        for (int l = 0; l < 16; ++l){
            float v = (Wg[l*6]*z0 + Wg[l*6+1]*z1 + bg[l] + theta[l]) * INV2PI;
            spx[l*LDSROW + lane] = padT ? 0.25f : v;   // pad: C=cos(pi/2)=0 -> state stays 0
        }
    }
    __syncthreads();

    // ---- Phase B: 24-step scan; px preloaded to registers (fully unrolled => static idx) ----
    const float* wr = Wg + sub*6;
    const float Wh0 = wr[2]*INV2PI, Wh1 = wr[3]*INV2PI, Wh2 = wr[4]*INV2PI, Wh3 = wr[5]*INV2PI;
    const bool isG  = (q == 2);
    const float kMul = isG ? (-2.0f*LOG2E) : (-LOG2E);
    const float aMul = isG ? 2.0f : 1.0f;
    const float aAdd = isG ? -1.0f : 0.0f;
    const bool bq1 = (q & 1) != 0, bq2 = (q & 2) != 0;
    const bool bmid = (q == 1) || (q == 2);
    const bool w_is0 = (w == 0), w_is1 = (w == 1), w_is2 = (w == 2);
    const bool doStore = (q == 0);

    float4 P[NCHUNK];
    {
        const float4* prow = reinterpret_cast<const float4*>(&spx[sub*LDSROW + 8*d]);
        #pragma unroll
        for (int i = 0; i < NCHUNK; ++i) P[i] = prow[i];
    }

    float cx = 0.0f, h0 = 0.0f, h1 = 0.0f, h2 = 0.0f, h3 = 0.0f;
    #pragma unroll
    for (int c = 0; c < NCHUNK; ++c){
        float4 cur = P[c];
        #pragma unroll
        for (int k = 0; k < 4; ++k){
            float px = (k==0) ? cur.x : (k==1) ? cur.y : (k==2) ? cur.z : cur.w;
            float m3 = Wh3*h3;
            float a1 = fmaf(Wh0, h0, px);
            float a2 = fmaf(Wh2, h2, m3);
            float a3 = fmaf(Wh1, h1, a1);
            float pre = a3 + a2;
            float u = __builtin_amdgcn_fractf(pre);
            float C = __builtin_amdgcn_cosf(u);
            float v1, v2, v3;
            DPP_F(v1, C, 0xB1);   // quad_perm [1,0,3,2] : lane^1
            DPP_F(v2, C, 0x4E);   // quad_perm [2,3,0,1] : lane^2
            DPP_F(v3, C, 0x1B);   // quad_perm [3,2,1,0] : lane^3
            float ta  = v2*v3;
            float p01 = C*v1;
            float sA = w_is0 ? v1 : (w_is2 ? C : p01);
            float zz = w_is1 ? sA : sA*ta;
            float e = __builtin_amdgcn_exp2f(zz * kMul);
            float r = __builtin_amdgcn_rcpf(1.0f + e);
            float A = fmaf(aMul, r, aAdd);
            float V8, tH, tF, V4, V12;
            DPP_F(V8, A, 0x128);      // row_ror:8  == lane^8 (within 16-lane row)
            DPP_F(tH, A, 0x141);      // row_half_mirror == lane^7
            DPP_F(tF, A, 0x140);      // row_mirror      == lane^15
            DPP_F(V4,  tH, 0x1B);     // ^7 then ^3 -> lane^4
            DPP_F(V12, tF, 0x1B);     // ^15 then ^3 -> lane^12
            float pa = V4*V8;
            float pb = A*V12;
            float Pig = bmid ? pb : pa;                // i * g
            float t1 = bq1 ? V4 : A;
            float t2 = bq1 ? V12 : V8;
            float A0 = bq2 ? t2 : t1;                  // f
            float u1 = bq1 ? V8 : V12;
            float u2 = bq1 ? A : V4;
            float A3 = bq2 ? u2 : u1;                  // o
            cx = fmaf(A0, cx, Pig);
            float e2 = __builtin_amdgcn_exp2f(cx * (2.0f*LOG2E));
            float r2 = __builtin_amdgcn_rcpf(1.0f + e2);
            float th = fmaf(-2.0f, r2, 1.0f);
            float hme = A3 * th;                       // h_w (same in all quads)
            if (c >= WARM/4 && doStore)
                hrow[(d*CH_OUT + (c*4 + k) - WARM)*4 + w] = hme;
            DPP_F(h0, hme, 0x00);
            DPP_F(h1, hme, 0x55);
            DPP_F(h2, hme, 0xAA);
            DPP_F(h3, hme, 0xFF);
        }
    }
    __syncthreads();

    // ---- Phase C: 4 rows per pass (row = lane>>4), 8 tags per lane, DPP rotate-reduce ----
    const int tg = (sub) * 8;                  // tags [tg, tg+8)
    float4 wv[8];
    #pragma unroll
    for (int j = 0; j < 8; ++j) wv[j] = *reinterpret_cast<const float4*>(Wtag + (tg + j)*4);
    float4 bv0 = *reinterpret_cast<const float4*>(btag + tg);
    float4 bv1 = *reinterpret_cast<const float4*>(btag + tg + 4);
    float bb[8] = {bv0.x, bv0.y, bv0.z, bv0.w, bv1.x, bv1.y, bv1.z, bv1.w};
    const float K = 1.4426950408889634f, LN2 = 0.6931471805599453f;
    float* outblk = out + (size_t)blockIdx.x * ROWS_PER_BLK * TAGS;

    #pragma unroll
    for (int pass = 0; pass < 8; ++pass){
        int rI = pass*4 + d;
        float4 h = *reinterpret_cast<const float4*>(&hrow[rI*4]);   // broadcast within 16-lane row
        float l[8];
        #pragma unroll
        for (int j = 0; j < 8; ++j)
            l[j] = fmaf(h.x, wv[j].x, fmaf(h.y, wv[j].y, fmaf(h.z, wv[j].z, fmaf(h.w, wv[j].w, bb[j]))));
        float m = fmaxf(fmaxf(fmaxf(l[0],l[1]), fmaxf(l[2],l[3])),
                        fmaxf(fmaxf(l[4],l[5]), fmaxf(l[6],l[7])));
        float o1;
        DPP_F(o1, m, 0x121); m = fmaxf(m, o1);   // row_ror:1
        DPP_F(o1, m, 0x122); m = fmaxf(m, o1);   // row_ror:2
        DPP_F(o1, m, 0x124); m = fmaxf(m, o1);   // row_ror:4
        DPP_F(o1, m, 0x128); m = fmaxf(m, o1);   // row_ror:8
        float e[8], s;
        #pragma unroll
        for (int j = 0; j < 8; ++j) e[j] = __builtin_amdgcn_exp2f((l[j] - m)*K);
        s = ((e[0]+e[1]) + (e[2]+e[3])) + ((e[4]+e[5]) + (e[6]+e[7]));
        DPP_F(o1, s, 0x121); s += o1;
        DPP_F(o1, s, 0x122); s += o1;
        DPP_F(o1, s, 0x124); s += o1;
        DPP_F(o1, s, 0x128); s += o1;
        float base = m + __builtin_amdgcn_logf(s) * LN2;
        float4 r0 = make_float4(l[0]-base, l[1]-base, l[2]-base, l[3]-base);
        float4 r1 = make_float4(l[4]-base, l[5]-base, l[6]-base, l[7]-base);
        float* orow = outblk + rI*TAGS + tg;
        *reinterpret_cast<float4*>(orow)     = r0;
        *reinterpret_cast<float4*>(orow + 4) = r1;
    }
}

extern "C" void kernel_launch(void* const* d_in, const int* in_sizes, int n_in,
                              void* d_out, int out_size, void* d_ws, size_t ws_size,
                              hipStream_t stream) {
    const float* emb   = (const float*)d_in[0];
    const float* Wg    = (const float*)d_in[1];
    const float* bg    = (const float*)d_in[2];
    const float* theta = (const float*)d_in[3];
    const float* Wtag  = (const float*)d_in[4];
    const float* btag  = (const float*)d_in[5];
    const int*   sent  = (const int*)d_in[6];
    float* out = (float*)d_out;

    // Fold the constant photonic circuit into a single 4x4 complex matrix (host, fp64)
    cd M[4][4];
    for (int i = 0; i < 4; ++i) for (int j = 0; j < 4; ++j) M[i][j] = (i==j) ? cd(1,0) : cd(0,0);
    fraud_h(M, 0.7, 0.3,  0.5,-0.4,  0.6,0.2, 0.8,-0.1,  0.4,0.1, 0.5,0.3,  0.2,-0.3);
    fraud_h(M, 0.9,-0.2,  0.3, 0.6,  0.5,0.4,-0.7, 0.2,  0.6,-0.2,-0.3,0.5, 0.4, 0.1);
    fraud_h(M,-0.5, 0.8, -0.6, 0.2,  0.3,-0.3,0.9, 0.5,  0.2, 0.6, 0.7,-0.4,-0.5, 0.3);
    MArg ma;
    for (int i = 0; i < 16; ++i){ ma.mr[i] = (float)M[i/4][i%4].real(); ma.mi[i] = (float)M[i/4][i%4].imag(); }

    k_fused<<<SEQ/ROWS_PER_BLK, 64, 0, stream>>>(emb, Wg, bg, theta, Wtag, btag, sent, out, ma);
}